// Round 16
// baseline (701.313 us; speedup 1.0000x reference)
//
#include <hip/hip_runtime.h>

typedef unsigned short u16;
typedef unsigned int u32;

#define DIM 64
#define NGRAPH 320
#define NPG 200
#define EPG 3200
#define EPG_P 5120  // padded capacity: 3200 + 3*200*3 <= 5000
#define NSTEPS 5
#define NITERS 6
#define NTILES 13  // ceil(200/16)
#define NPAD 208   // NTILES*16
#define NTHR 1024  // 16 waves (best measured config family: R7/R11/R12/R15)

typedef __attribute__((ext_vector_type(8))) short bf16x8;
typedef __attribute__((ext_vector_type(4))) float f32x4;

__device__ __forceinline__ float bf2f(u16 u) {
  u32 x = ((u32)u) << 16;
  float f;
  __builtin_memcpy(&f, &x, 4);
  return f;
}
__device__ __forceinline__ u16 f2bf(float f) {
  u32 x;
  __builtin_memcpy(&x, &f, 4);
  x = (x + 0x7FFFu + ((x >> 16) & 1u)) >> 16;
  return (u16)x;
}
__device__ __forceinline__ float bflo(u32 w) {
  u32 x = w << 16;
  float f;
  __builtin_memcpy(&f, &x, 4);
  return f;
}
__device__ __forceinline__ float bfhi(u32 w) {
  u32 x = w & 0xffff0000u;
  float f;
  __builtin_memcpy(&f, &x, 4);
  return f;
}
__device__ __forceinline__ float sigmf(float x) { return 1.0f / (1.0f + __expf(-x)); }
// XOR swizzle for bf16 [row][64] LDS tiles read as ds_read_b128 at 128B row stride.
__device__ __forceinline__ int swz(int row, int col) { return row * 64 + (col ^ ((row & 7) << 3)); }

#define REP13(M) M(0) M(1) M(2) M(3) M(4) M(5) M(6) M(7) M(8) M(9) M(10) M(11) M(12)

// ---------------- prep ----------------

// 3-phase CSR, PADDED: phase p = etype>>1. Each (phase,node) edge list padded to
// a multiple of 4 with sentinel rec=200 (wh half0 row 200 = zeros): uniform
// 4-wide gather loop, no tails. rec = (etype&1)*208 + src.
__global__ void __launch_bounds__(256) k_csr(const int* __restrict__ src,
                                             const int* __restrict__ dst,
                                             const int* __restrict__ ety,
                                             u16* __restrict__ recs,
                                             int* __restrict__ rows) {
  __shared__ int cnt[3 * NPG];
  __shared__ int rofs[3 * (NPG + 1)];
  int g = blockIdx.x, tid = threadIdx.x;
  int base = g * NPG;
  for (int i = tid; i < 3 * NPG; i += 256) cnt[i] = 0;
  __syncthreads();
  for (int e = tid; e < EPG; e += 256) {
    int d = dst[g * EPG + e] - base;
    int t = ety[g * EPG + e];
    atomicAdd(&cnt[(t >> 1) * NPG + d], 1);
  }
  __syncthreads();
  if (tid == 0) {
    int s = 0;
    for (int p = 0; p < 3; p++) {
      for (int n = 0; n < NPG; n++) {
        rofs[p * (NPG + 1) + n] = s;
        s += (cnt[p * NPG + n] + 3) & ~3;  // pad to x4
      }
      rofs[p * (NPG + 1) + NPG] = s;
    }
  }
  __syncthreads();
  for (int i = tid; i < 3 * NPG; i += 256) cnt[i] = rofs[(i / NPG) * (NPG + 1) + (i % NPG)];
  __syncthreads();
  for (int e = tid; e < EPG; e += 256) {
    int d = dst[g * EPG + e] - base;
    int t = ety[g * EPG + e];
    int sl = src[g * EPG + e] - base;
    int pos = atomicAdd(&cnt[(t >> 1) * NPG + d], 1);
    recs[(size_t)g * EPG_P + pos] = (u16)((t & 1) * NPAD + sl);
  }
  __syncthreads();
  // sentinel-fill the padding slots
  for (int i = tid; i < 3 * NPG; i += 256) {
    int ph = i / NPG, n = i % NPG;
    int end = rofs[ph * (NPG + 1) + n + 1];
    for (int p = cnt[i]; p < end; p++) recs[(size_t)g * EPG_P + p] = (u16)NPG;  // row 200 = zeros
  }
  for (int i = tid; i < 3 * (NPG + 1); i += 256) rows[g * 3 * (NPG + 1) + i] = rofs[i];
}

// All weight conversions/transposes in ONE launch (163840 elems = 640 x 256).
__global__ void __launch_bounds__(256) k_prep(
    const float* __restrict__ W_edge, const float* __restrict__ gWih, const float* __restrict__ gWhh,
    const float* __restrict__ lWi0, const float* __restrict__ lWh0,
    const float* __restrict__ lWi1, const float* __restrict__ lWh1,
    const float* __restrict__ lWi2, const float* __restrict__ lWh2,
    u16* __restrict__ WeTb, u16* __restrict__ Wihb, u16* __restrict__ Whhb,
    u16* __restrict__ WTih0b, u16* __restrict__ WThh0b,
    u16* __restrict__ WTih1b, u16* __restrict__ WThh1b,
    u16* __restrict__ WTih2b, u16* __restrict__ WThh2b) {
  int i = blockIdx.x * 256 + threadIdx.x;
  if (i < 24576) {  // WeT: [t][o][k] <- W_edge[t][k][o]
    int t = i >> 12, rem = i & 4095, o = rem >> 6, k = rem & 63;
    WeTb[i] = f2bf(W_edge[t * 4096 + k * 64 + o]);
  } else if (i < 36864) {
    int idx = i - 24576;
    Wihb[idx] = f2bf(gWih[idx]);
  } else if (i < 49152) {
    int idx = i - 36864;
    Whhb[idx] = f2bf(gWhh[idx]);
  } else if (i < 81920) {  // WTih0: [k<128][j<256] <- lWi0[j][k]
    int idx = i - 49152;
    int k = idx >> 8, jj = idx & 255;
    WTih0b[idx] = f2bf(lWi0[jj * 128 + k]);
  } else {  // five [k<64][j<256] transposes
    int idx = i - 81920;
    int seg = idx >> 14;
    int r = idx & 16383;
    int k = r >> 8, jj = r & 255;
    const float* sp = seg == 0 ? lWh0 : seg == 1 ? lWi1 : seg == 2 ? lWh1 : seg == 3 ? lWi2 : lWh2;
    u16* dp = seg == 0 ? WThh0b : seg == 1 ? WTih1b : seg == 2 ? WThh1b : seg == 3 ? WTih2b : WThh2b;
    dp[r] = f2bf(sp[jj * 64 + k]);
  }
}

// ---------------- fully fused GGNN + Set2Set: one block = one graph ----------------
// R16 = R15 (best: 573us) + cross-node pipelined gather. R15's residual is exposed
// LDS-chain latency: 13 sequential per-node loops avg only ~1.7 trips each, so the
// rec->addr->wh chain (~240cy) restarts cold 13x/phase with no overlap. GATHER2
// fuses node pairs (wave-uniform bounds) into one loop with per-trip rec prefetch:
// 4 wh + 4 rec loads in flight per pair-trip, exposed latency ~halved.

__global__ void __launch_bounds__(NTHR) k_ggnn(
    const float* __restrict__ feats,
    const u16* __restrict__ WeTb, const float* __restrict__ b_edge,
    const u16* __restrict__ Wihb, const u16* __restrict__ Whhb,
    const float* __restrict__ gbih, const float* __restrict__ gbhh,
    const u16* __restrict__ recs, const int* __restrict__ rows,
    const u16* __restrict__ WTih0b, const u16* __restrict__ WThh0b,
    const u16* __restrict__ WTih1b, const u16* __restrict__ WThh1b,
    const u16* __restrict__ WTih2b, const u16* __restrict__ WThh2b,
    const float* __restrict__ b_ih0, const float* __restrict__ b_hh0,
    const float* __restrict__ b_ih1, const float* __restrict__ b_hh1,
    const float* __restrict__ b_ih2, const float* __restrict__ b_hh2,
    const float* __restrict__ Wp, const float* __restrict__ bp,
    float* __restrict__ out) {
  __shared__ __align__(16) u16 hb_s[NPAD * 64];      // bf16 h (swizzled)   26624B
  __shared__ __align__(16) u16 wh_s[2 * NPAD * 64];  // 2-etype Wh / ab     53248B
  __shared__ __align__(16) float h32_s[NPG * 64];    // fp32 h / feat_s     51200B
  __shared__ __align__(16) char u_s[12656];          // rec+rows | s2s      12656B
  // total ~143.7KB -> 1 block/CU

  u16* rec_s = (u16*)u_s;               // 10240B (steps)
  int* rows_s = (int*)(u_s + 10240);    //  2412B (steps)
  float* qstar = (float*)u_s;           // s2s overlay:
  float* xbuf = (float*)(u_s + 512);    //
  float* hs_f = (float*)(u_s + 768);    // [3][64]
  float* cs_f = (float*)(u_s + 1536);   // [3][64]
  float* gates = (float*)(u_s + 2304);  // [256]
  float* gpart = (float*)(u_s + 3328);  // [4][256]
  float* e_s = (float*)(u_s + 7424);    // [200]
  float* red_f = (float*)(u_s + 8224);  // [16][64]
  float* scal = (float*)(u_s + 12320);  // [2]

  int g = blockIdx.x, tid = threadIdx.x;
  int lane = tid & 63, wid = tid >> 6;  // 16 waves
  int m = lane & 15, quad = lane >> 4;
  int half = lane >> 5, l32 = lane & 31;

  // ---- stage graph-local state ----
  const float* fg = feats + (size_t)g * (NPG * 64);
  for (int i = tid; i < NPG * 64; i += NTHR) {
    float v = fg[i];
    h32_s[i] = v;
    hb_s[swz(i >> 6, i & 63)] = f2bf(v);
  }
  for (int i = tid; i < (NPAD - NPG) * 64; i += NTHR) hb_s[NPG * 64 + i] = 0;  // pad rows
  // zero wh pad rows 200..207 of BOTH halves (preserved: nothing else writes them)
  for (int i = tid; i < 2 * 8 * 64; i += NTHR) {
    int tl = i >> 9, rem = i & 511;
    wh_s[(tl * NPAD + NPG + (rem >> 6)) * 64 + (rem & 63)] = 0;
  }
  {
    const u32* r32 = (const u32*)(recs + (size_t)g * EPG_P);
    u32* rl = (u32*)rec_s;
    for (int i = tid; i < EPG_P / 2; i += NTHR) rl[i] = r32[i];
  }
  for (int i = tid; i < 3 * (NPG + 1); i += NTHR) rows_s[i] = rows[g * 3 * (NPG + 1) + i];

  u16* ab_s = wh_s;  // alias: wh dead once gathers finish; flush writes rows<200 only
  int ot = wid & 3, hh = wid >> 2;  // hh in 0..3

// 13 named gather accumulator pairs: node n = q*16+wid, 2 cols per lane,
// accumulated across ALL 3 phases, halves combined at flush.
#define ACC_DECL(q) float a0_##q, a1_##q;
  REP13(ACC_DECL)
#define ACC_ZERO(q) a0_##q = 0.f; a1_##q = 0.f;

// Pair-fused gather: nodes qa,qb processed in ONE loop (bounds wave-uniform),
// rec indices prefetched one trip ahead -> 4 wh + 4 rec loads in flight.
#define GATHER2(qa, qb)                                          \
  {                                                              \
    int na = (qa)*16 + wid;                                      \
    int nb = (qb)*16 + wid;                                      \
    int ea = rowp[na], ra = rowp[na + 1];                        \
    int eb = rowp[nb], rb = rowp[nb + 1];                        \
    int pAa = 0, pBa = 0, pAb = 0, pBb = 0;                      \
    if (ea < ra) { pAa = rec_s[ea + half]; pBa = rec_s[ea + 2 + half]; } \
    if (eb < rb) { pAb = rec_s[eb + half]; pBb = rec_s[eb + 2 + half]; } \
    while (ea < ra || eb < rb) {                                 \
      if (ea < ra) {                                             \
        u32 wA = *(const u32*)(wh_s + pAa * 64 + 2 * l32);       \
        u32 wB = *(const u32*)(wh_s + pBa * 64 + 2 * l32);       \
        ea += 4;                                                 \
        if (ea < ra) { pAa = rec_s[ea + half]; pBa = rec_s[ea + 2 + half]; } \
        a0_##qa += bflo(wA) + bflo(wB);                          \
        a1_##qa += bfhi(wA) + bfhi(wB);                          \
      }                                                          \
      if (eb < rb) {                                             \
        u32 wA = *(const u32*)(wh_s + pAb * 64 + 2 * l32);       \
        u32 wB = *(const u32*)(wh_s + pBb * 64 + 2 * l32);       \
        eb += 4;                                                 \
        if (eb < rb) { pAb = rec_s[eb + half]; pBb = rec_s[eb + 2 + half]; } \
        a0_##qb += bflo(wA) + bflo(wB);                          \
        a1_##qb += bfhi(wA) + bfhi(wB);                          \
      }                                                          \
    }                                                            \
  }
// Single-node tail (q=12: node 192+wid valid only for wid<8), prefetch-pipelined.
#define GATHER1(q)                                               \
  {                                                              \
    int n = (q)*16 + wid;                                        \
    if (n < NPG) {                                               \
      int e = rowp[n], re = rowp[n + 1];                         \
      int pA = 0, pB = 0;                                        \
      if (e < re) { pA = rec_s[e + half]; pB = rec_s[e + 2 + half]; } \
      while (e < re) {                                           \
        u32 wA = *(const u32*)(wh_s + pA * 64 + 2 * l32);        \
        u32 wB = *(const u32*)(wh_s + pB * 64 + 2 * l32);        \
        e += 4;                                                  \
        if (e < re) { pA = rec_s[e + half]; pB = rec_s[e + 2 + half]; } \
        a0_##q += bflo(wA) + bflo(wB);                           \
        a1_##q += bfhi(wA) + bfhi(wB);                           \
      }                                                          \
    }                                                            \
  }
#define FLUSH(q)                                                   \
  {                                                                \
    int n = (q)*16 + wid;                                          \
    float s0 = a0_##q + __shfl_xor(a0_##q, 32);                    \
    float s1 = a1_##q + __shfl_xor(a1_##q, 32);                    \
    if (n < NPG && lane < 32) {                                    \
      u32 pk = (u32)f2bf(s0) | ((u32)f2bf(s1) << 16);              \
      *(u32*)(ab_s + n * 64 + ((2 * l32) ^ ((n & 7) << 3))) = pk;  \
    }                                                              \
  }

#pragma unroll 1
  for (int step = 0; step < NSTEPS; step++) {
    REP13(ACC_ZERO)
#pragma unroll 1
    for (int ph = 0; ph < 3; ph++) {
      __syncthreads();  // wh_s/ab_s free (prev gather read / prev GRU read / staging)
      // ---- transform etypes {2ph, 2ph+1} -> wh_s halves ----
      // B-fragments reloaded from L2 per iteration (NOT hoisted): keeps the 26
      // gather accs register-resident across the transform (R12 spilled them).
      for (int nt = hh; nt < NTILES; nt += 4) {  // tl = 0
        const u16* bp0 = WeTb + (((2 * ph) * 64 + ot * 16 + m) * 64) + quad * 8;
        bf16x8 B00 = *(const bf16x8*)bp0;
        bf16x8 B01 = *(const bf16x8*)(bp0 + 32);
        int arow = nt * 16 + m;
        bf16x8 a0 = *(const bf16x8*)(hb_s + swz(arow, quad * 8));
        bf16x8 a1 = *(const bf16x8*)(hb_s + swz(arow, quad * 8 + 32));
        f32x4 c = {0.f, 0.f, 0.f, 0.f};
        c = __builtin_amdgcn_mfma_f32_16x16x32_bf16(a0, B00, c, 0, 0, 0);
        c = __builtin_amdgcn_mfma_f32_16x16x32_bf16(a1, B01, c, 0, 0, 0);
        float bias0 = b_edge[(2 * ph) * 64 + ot * 16 + m];
#pragma unroll
        for (int r = 0; r < 4; r++) {
          int node = nt * 16 + quad * 4 + r;
          if (node < NPG) wh_s[node * 64 + ot * 16 + m] = f2bf(c[r] + bias0);
        }
      }
      for (int nt = 3 - hh; nt < NTILES; nt += 4) {  // tl = 1 (reversed for balance)
        const u16* bp1 = WeTb + (((2 * ph + 1) * 64 + ot * 16 + m) * 64) + quad * 8;
        bf16x8 B10 = *(const bf16x8*)bp1;
        bf16x8 B11 = *(const bf16x8*)(bp1 + 32);
        int arow = nt * 16 + m;
        bf16x8 a0 = *(const bf16x8*)(hb_s + swz(arow, quad * 8));
        bf16x8 a1 = *(const bf16x8*)(hb_s + swz(arow, quad * 8 + 32));
        f32x4 c = {0.f, 0.f, 0.f, 0.f};
        c = __builtin_amdgcn_mfma_f32_16x16x32_bf16(a0, B10, c, 0, 0, 0);
        c = __builtin_amdgcn_mfma_f32_16x16x32_bf16(a1, B11, c, 0, 0, 0);
        float bias1 = b_edge[(2 * ph + 1) * 64 + ot * 16 + m];
#pragma unroll
        for (int r = 0; r < 4; r++) {
          int node = nt * 16 + quad * 4 + r;
          if (node < NPG) wh_s[(NPAD + node) * 64 + ot * 16 + m] = f2bf(c[r] + bias1);
        }
      }
      __syncthreads();  // wh ready
      // ---- gather: pair-fused, prefetch-pipelined ----
      const int* rowp = rows_s + ph * (NPG + 1);
      GATHER2(0, 1)
      GATHER2(2, 3)
      GATHER2(4, 5)
      GATHER2(6, 7)
      GATHER2(8, 9)
      GATHER2(10, 11)
      GATHER1(12)
    }
    __syncthreads();  // all gathers done reading wh_s -> reuse as ab_s
    REP13(FLUSH)
    __syncthreads();  // ab ready
    // ---- GRU: wave wid owns tile nt=wid; per-dq fragments (16 acc regs) ----
    if (wid < NTILES) {
      int nt = wid;
      int arow = nt * 16 + m;
      bf16x8 aa0 = *(const bf16x8*)(ab_s + swz(arow, quad * 8));
      bf16x8 aa1 = *(const bf16x8*)(ab_s + swz(arow, quad * 8 + 32));
      bf16x8 ah0 = *(const bf16x8*)(hb_s + swz(arow, quad * 8));
      bf16x8 ah1 = *(const bf16x8*)(hb_s + swz(arow, quad * 8 + 32));
#pragma unroll
      for (int dq = 0; dq < 4; dq++) {
        int d = dq * 16 + m;
        f32x4 z4 = {0.f, 0.f, 0.f, 0.f};
        const u16* bi = Wihb + (dq * 16 + m) * 64 + quad * 8;
        const u16* bh = Whhb + (dq * 16 + m) * 64 + quad * 8;
        f32x4 cr = z4;
        {
          bf16x8 b0 = *(const bf16x8*)bi, b1 = *(const bf16x8*)(bi + 32);
          bf16x8 c0 = *(const bf16x8*)bh, c1 = *(const bf16x8*)(bh + 32);
          cr = __builtin_amdgcn_mfma_f32_16x16x32_bf16(ah0, c0, cr, 0, 0, 0);
          cr = __builtin_amdgcn_mfma_f32_16x16x32_bf16(ah1, c1, cr, 0, 0, 0);
          cr = __builtin_amdgcn_mfma_f32_16x16x32_bf16(aa0, b0, cr, 0, 0, 0);
          cr = __builtin_amdgcn_mfma_f32_16x16x32_bf16(aa1, b1, cr, 0, 0, 0);
        }
        const u16* bi2 = Wihb + ((4 + dq) * 16 + m) * 64 + quad * 8;
        const u16* bh2 = Whhb + ((4 + dq) * 16 + m) * 64 + quad * 8;
        f32x4 cz = z4;
        {
          bf16x8 b0 = *(const bf16x8*)bi2, b1 = *(const bf16x8*)(bi2 + 32);
          bf16x8 c0 = *(const bf16x8*)bh2, c1 = *(const bf16x8*)(bh2 + 32);
          cz = __builtin_amdgcn_mfma_f32_16x16x32_bf16(ah0, c0, cz, 0, 0, 0);
          cz = __builtin_amdgcn_mfma_f32_16x16x32_bf16(ah1, c1, cz, 0, 0, 0);
          cz = __builtin_amdgcn_mfma_f32_16x16x32_bf16(aa0, b0, cz, 0, 0, 0);
          cz = __builtin_amdgcn_mfma_f32_16x16x32_bf16(aa1, b1, cz, 0, 0, 0);
        }
        const u16* bi3 = Wihb + ((8 + dq) * 16 + m) * 64 + quad * 8;
        const u16* bh3 = Whhb + ((8 + dq) * 16 + m) * 64 + quad * 8;
        f32x4 ci = z4, ch = z4;
        {
          bf16x8 b0 = *(const bf16x8*)bi3, b1 = *(const bf16x8*)(bi3 + 32);
          bf16x8 c0 = *(const bf16x8*)bh3, c1 = *(const bf16x8*)(bh3 + 32);
          ci = __builtin_amdgcn_mfma_f32_16x16x32_bf16(aa0, b0, ci, 0, 0, 0);
          ci = __builtin_amdgcn_mfma_f32_16x16x32_bf16(aa1, b1, ci, 0, 0, 0);
          ch = __builtin_amdgcn_mfma_f32_16x16x32_bf16(ah0, c0, ch, 0, 0, 0);
          ch = __builtin_amdgcn_mfma_f32_16x16x32_bf16(ah1, c1, ch, 0, 0, 0);
        }
        float bi_r = gbih[d], bh_r = gbhh[d];
        float bi_z = gbih[64 + d], bh_z = gbhh[64 + d];
        float bi_n = gbih[128 + d], bh_n = gbhh[128 + d];
#pragma unroll
        for (int r = 0; r < 4; r++) {
          int node = nt * 16 + quad * 4 + r;
          if (node < NPG) {
            float rr = sigmf(cr[r] + bi_r + bh_r);
            float zz = sigmf(cz[r] + bi_z + bh_z);
            float nn = tanhf(ci[r] + bi_n + rr * (ch[r] + bh_n));
            float hv = h32_s[node * 64 + d];
            float hnew = (1.0f - zz) * nn + zz * hv;
            h32_s[node * 64 + d] = hnew;
            hb_s[swz(node, d)] = f2bf(hnew);
          }
        }
      }
    }
  }
  __syncthreads();  // final h (feat_s = h32_s) ready; u_s becomes s2s scratch
  const float* feat_s = h32_s;

  // ================= Set2Set: 4-part matvec, weights streamed from L2 =================
  int j = tid & 255, part = tid >> 8;  // wave-uniform part in 0..3
  float bs0 = 0.f, bs1 = 0.f, bs2 = 0.f;
  if (tid < 256) {
    bs0 = b_ih0[tid] + b_hh0[tid];
    bs1 = b_ih1[tid] + b_hh1[tid];
    bs2 = b_ih2[tid] + b_hh2[tid];
  }
  __syncthreads();  // rec_s/rows_s dead before overlay writes
  if (tid < 128) qstar[tid] = 0.f;
  if (tid < 64) {
    xbuf[tid] = 0.f;
    for (int l = 0; l < 3; l++) {
      hs_f[l * 64 + tid] = 0.f;
      cs_f[l * 64 + tid] = 0.f;
    }
  }
  __syncthreads();
#pragma unroll 1
  for (int it = 0; it < NITERS; it++) {
    // ---- layer 0 ----
    {
      float a0 = 0.f;
      if (part == 0) {
#pragma unroll 8
        for (int k = 0; k < 48; k++) a0 += qstar[k] * bf2f(WTih0b[k * 256 + j]);
      } else if (part == 1) {
#pragma unroll 8
        for (int k = 48; k < 96; k++) a0 += qstar[k] * bf2f(WTih0b[k * 256 + j]);
      } else if (part == 2) {
#pragma unroll 8
        for (int k = 96; k < 128; k++) a0 += qstar[k] * bf2f(WTih0b[k * 256 + j]);
#pragma unroll 8
        for (int k = 0; k < 16; k++) a0 += hs_f[k] * bf2f(WThh0b[k * 256 + j]);
      } else {
#pragma unroll 8
        for (int k = 16; k < 64; k++) a0 += hs_f[k] * bf2f(WThh0b[k * 256 + j]);
      }
      gpart[part * 256 + j] = a0;
    }
    __syncthreads();
    if (tid < 256)
      gates[tid] = gpart[tid] + gpart[256 + tid] + gpart[512 + tid] + gpart[768 + tid] + bs0;
    __syncthreads();
    if (tid < 64) {
      float cc = sigmf(gates[64 + tid]) * cs_f[tid] + sigmf(gates[tid]) * tanhf(gates[128 + tid]);
      float x = sigmf(gates[192 + tid]) * tanhf(cc);
      cs_f[tid] = cc;
      hs_f[tid] = x;
      xbuf[tid] = x;
    }
    __syncthreads();
    // ---- layers 1,2 ----
#pragma unroll 1
    for (int l = 1; l < 3; l++) {
      const u16* W = (l == 1) ? ((part < 2) ? WTih1b : WThh1b)
                              : ((part < 2) ? WTih2b : WThh2b);
      const float* xv = (part < 2) ? xbuf : (hs_f + l * 64);
      int k0 = (part & 1) * 32;
      float a0 = 0.f;
#pragma unroll 8
      for (int k = k0; k < k0 + 32; k++) a0 += xv[k] * bf2f(W[k * 256 + j]);
      gpart[part * 256 + j] = a0;
      __syncthreads();
      float bsl = (l == 1) ? bs1 : bs2;
      if (tid < 256)
        gates[tid] = gpart[tid] + gpart[256 + tid] + gpart[512 + tid] + gpart[768 + tid] + bsl;
      __syncthreads();
      if (tid < 64) {
        float cc = sigmf(gates[64 + tid]) * cs_f[l * 64 + tid] +
                   sigmf(gates[tid]) * tanhf(gates[128 + tid]);
        float x = sigmf(gates[192 + tid]) * tanhf(cc);
        cs_f[l * 64 + tid] = cc;
        hs_f[l * 64 + tid] = x;
        xbuf[tid] = x;
      }
      __syncthreads();
    }
    // ---- attention over this graph's nodes ----
    for (int n = wid; n < NPG; n += 16) {
      float v = feat_s[n * 64 + lane] * xbuf[lane];
      for (int off = 32; off > 0; off >>= 1) v += __shfl_down(v, off);
      if (lane == 0) e_s[n] = v;
    }
    __syncthreads();
    if (tid < 64) {
      float mx = -1e30f;
      for (int n = lane; n < NPG; n += 64) mx = fmaxf(mx, e_s[n]);
      for (int off = 32; off > 0; off >>= 1) mx = fmaxf(mx, __shfl_down(mx, off));
      mx = __shfl(mx, 0);
      float ssum = 0.f;
      for (int n = lane; n < NPG; n += 64) {
        float ex = __expf(e_s[n] - mx);
        e_s[n] = ex;
        ssum += ex;
      }
      for (int off = 32; off > 0; off >>= 1) ssum += __shfl_down(ssum, off);
      if (lane == 0) scal[0] = ssum;
    }
    __syncthreads();
    float denom = scal[0];
    {
      float r = 0.f;
      for (int n = wid; n < NPG; n += 16) r += feat_s[n * 64 + lane] * e_s[n];
      red_f[wid * 64 + lane] = r;
    }
    __syncthreads();
    if (tid < 64) {
      float ro = 0.f;
#pragma unroll
      for (int ww = 0; ww < 16; ww++) ro += red_f[ww * 64 + lane];
      qstar[lane] = xbuf[lane];
      qstar[64 + lane] = ro / denom;
    }
    __syncthreads();
  }
  if (tid < 3) {
    float s = bp[tid];
    for (int k = 0; k < 128; k++) s += qstar[k] * Wp[tid * 128 + k];
    out[g * 3 + tid] = s;
  }
}

// ---------------- host ----------------

extern "C" void kernel_launch(void* const* d_in, const int* in_sizes, int n_in,
                              void* d_out, int out_size, void* d_ws, size_t ws_size,
                              hipStream_t stream) {
  const float* feats  = (const float*)d_in[0];
  const float* W_edge = (const float*)d_in[1];
  const float* b_edge = (const float*)d_in[2];
  const float* gWih   = (const float*)d_in[3];
  const float* gWhh   = (const float*)d_in[4];
  const float* gbih   = (const float*)d_in[5];
  const float* gbhh   = (const float*)d_in[6];
  const float* lWi0   = (const float*)d_in[7];
  const float* lWh0   = (const float*)d_in[8];
  const float* lbi0   = (const float*)d_in[9];
  const float* lbh0   = (const float*)d_in[10];
  const float* lWi1   = (const float*)d_in[11];
  const float* lWh1   = (const float*)d_in[12];
  const float* lbi1   = (const float*)d_in[13];
  const float* lbh1   = (const float*)d_in[14];
  const float* lWi2   = (const float*)d_in[15];
  const float* lWh2   = (const float*)d_in[16];
  const float* lbi2   = (const float*)d_in[17];
  const float* lbh2   = (const float*)d_in[18];
  const float* Wp     = (const float*)d_in[19];
  const float* bp     = (const float*)d_in[20];
  const int* src      = (const int*)d_in[21];
  const int* dst      = (const int*)d_in[22];
  const int* ety      = (const int*)d_in[23];
  float* out = (float*)d_out;

  char* ws = (char*)d_ws;
  u16* recs    = (u16*)ws;              // 3,276,800 B (320 x 5120 x 2)
  int* rows    = (int*)(ws + 3276800);  //   771,840 B (320 x 3 x 201)
  u16* WeTb    = (u16*)(ws + 4048640);  //    49,152 B
  u16* Wihb    = (u16*)(ws + 4097792);  //    24,576 B
  u16* Whhb    = (u16*)(ws + 4122368);  //    24,576 B
  u16* WTih0b  = (u16*)(ws + 4146944);  //    65,536 B
  u16* WThh0b  = (u16*)(ws + 4212480);  //    32,768 B
  u16* WTih1b  = (u16*)(ws + 4245248);  //    32,768 B
  u16* WThh1b  = (u16*)(ws + 4278016);  //    32,768 B
  u16* WTih2b  = (u16*)(ws + 4310784);  //    32,768 B
  u16* WThh2b  = (u16*)(ws + 4343552);  //    32,768 B

  k_csr<<<NGRAPH, 256, 0, stream>>>(src, dst, ety, recs, rows);
  k_prep<<<640, 256, 0, stream>>>(W_edge, gWih, gWhh, lWi0, lWh0, lWi1, lWh1, lWi2, lWh2,
                                  WeTb, Wihb, Whhb, WTih0b, WThh0b, WTih1b, WThh1b, WTih2b, WThh2b);
  k_ggnn<<<NGRAPH, NTHR, 0, stream>>>(feats, WeTb, b_edge, Wihb, Whhb, gbih, gbhh, recs, rows,
                                      WTih0b, WThh0b, WTih1b, WThh1b, WTih2b, WThh2b,
                                      lbi0, lbh0, lbi1, lbh1, lbi2, lbh2, Wp, bp, out);
}

// Round 17
// 683.495 us; speedup vs baseline: 1.0261x; 1.0261x over previous
//
#include <hip/hip_runtime.h>

typedef unsigned short u16;
typedef unsigned int u32;

#define DIM 64
#define NGRAPH 320
#define NPG 200
#define EPG 3200
#define EPG_P 5120  // padded capacity: 3200 + 3*200*3 <= 5000
#define NSTEPS 5
#define NITERS 6
#define NTILES 13  // ceil(200/16)
#define NPAD 208   // NTILES*16
#define NTHR 1024  // 16 waves (best measured config family: R7/R11/R12/R15)

typedef __attribute__((ext_vector_type(8))) short bf16x8;
typedef __attribute__((ext_vector_type(4))) float f32x4;

__device__ __forceinline__ float bf2f(u16 u) {
  u32 x = ((u32)u) << 16;
  float f;
  __builtin_memcpy(&f, &x, 4);
  return f;
}
__device__ __forceinline__ u16 f2bf(float f) {
  u32 x;
  __builtin_memcpy(&x, &f, 4);
  x = (x + 0x7FFFu + ((x >> 16) & 1u)) >> 16;
  return (u16)x;
}
__device__ __forceinline__ float bflo(u32 w) {
  u32 x = w << 16;
  float f;
  __builtin_memcpy(&f, &x, 4);
  return f;
}
__device__ __forceinline__ float bfhi(u32 w) {
  u32 x = w & 0xffff0000u;
  float f;
  __builtin_memcpy(&f, &x, 4);
  return f;
}
__device__ __forceinline__ float sigmf(float x) { return 1.0f / (1.0f + __expf(-x)); }
// XOR swizzle for bf16 [row][64] LDS tiles read as ds_read_b128 at 128B row stride.
__device__ __forceinline__ int swz(int row, int col) { return row * 64 + (col ^ ((row & 7) << 3)); }

#define REP13(M) M(0) M(1) M(2) M(3) M(4) M(5) M(6) M(7) M(8) M(9) M(10) M(11) M(12)

// ---------------- prep ----------------

// 3-phase CSR, PADDED: phase p = etype>>1. Each (phase,node) edge list padded to
// a multiple of 4 with sentinel rec=200 (wh half0 row 200 = zeros): uniform
// 4-wide gather loop, no tails. rec = (etype&1)*208 + src.
__global__ void __launch_bounds__(256) k_csr(const int* __restrict__ src,
                                             const int* __restrict__ dst,
                                             const int* __restrict__ ety,
                                             u16* __restrict__ recs,
                                             int* __restrict__ rows) {
  __shared__ int cnt[3 * NPG];
  __shared__ int rofs[3 * (NPG + 1)];
  int g = blockIdx.x, tid = threadIdx.x;
  int base = g * NPG;
  for (int i = tid; i < 3 * NPG; i += 256) cnt[i] = 0;
  __syncthreads();
  for (int e = tid; e < EPG; e += 256) {
    int d = dst[g * EPG + e] - base;
    int t = ety[g * EPG + e];
    atomicAdd(&cnt[(t >> 1) * NPG + d], 1);
  }
  __syncthreads();
  if (tid == 0) {
    int s = 0;
    for (int p = 0; p < 3; p++) {
      for (int n = 0; n < NPG; n++) {
        rofs[p * (NPG + 1) + n] = s;
        s += (cnt[p * NPG + n] + 3) & ~3;  // pad to x4
      }
      rofs[p * (NPG + 1) + NPG] = s;
    }
  }
  __syncthreads();
  for (int i = tid; i < 3 * NPG; i += 256) cnt[i] = rofs[(i / NPG) * (NPG + 1) + (i % NPG)];
  __syncthreads();
  for (int e = tid; e < EPG; e += 256) {
    int d = dst[g * EPG + e] - base;
    int t = ety[g * EPG + e];
    int sl = src[g * EPG + e] - base;
    int pos = atomicAdd(&cnt[(t >> 1) * NPG + d], 1);
    recs[(size_t)g * EPG_P + pos] = (u16)((t & 1) * NPAD + sl);
  }
  __syncthreads();
  // sentinel-fill the padding slots
  for (int i = tid; i < 3 * NPG; i += 256) {
    int ph = i / NPG, n = i % NPG;
    int end = rofs[ph * (NPG + 1) + n + 1];
    for (int p = cnt[i]; p < end; p++) recs[(size_t)g * EPG_P + p] = (u16)NPG;  // row 200 = zeros
  }
  for (int i = tid; i < 3 * (NPG + 1); i += 256) rows[g * 3 * (NPG + 1) + i] = rofs[i];
}

// All weight conversions/transposes in ONE launch (163840 elems = 640 x 256).
__global__ void __launch_bounds__(256) k_prep(
    const float* __restrict__ W_edge, const float* __restrict__ gWih, const float* __restrict__ gWhh,
    const float* __restrict__ lWi0, const float* __restrict__ lWh0,
    const float* __restrict__ lWi1, const float* __restrict__ lWh1,
    const float* __restrict__ lWi2, const float* __restrict__ lWh2,
    u16* __restrict__ WeTb, u16* __restrict__ Wihb, u16* __restrict__ Whhb,
    u16* __restrict__ WTih0b, u16* __restrict__ WThh0b,
    u16* __restrict__ WTih1b, u16* __restrict__ WThh1b,
    u16* __restrict__ WTih2b, u16* __restrict__ WThh2b) {
  int i = blockIdx.x * 256 + threadIdx.x;
  if (i < 24576) {  // WeT: [t][o][k] <- W_edge[t][k][o]
    int t = i >> 12, rem = i & 4095, o = rem >> 6, k = rem & 63;
    WeTb[i] = f2bf(W_edge[t * 4096 + k * 64 + o]);
  } else if (i < 36864) {
    int idx = i - 24576;
    Wihb[idx] = f2bf(gWih[idx]);
  } else if (i < 49152) {
    int idx = i - 36864;
    Whhb[idx] = f2bf(gWhh[idx]);
  } else if (i < 81920) {  // WTih0: [k<128][j<256] <- lWi0[j][k]
    int idx = i - 49152;
    int k = idx >> 8, jj = idx & 255;
    WTih0b[idx] = f2bf(lWi0[jj * 128 + k]);
  } else {  // five [k<64][j<256] transposes
    int idx = i - 81920;
    int seg = idx >> 14;
    int r = idx & 16383;
    int k = r >> 8, jj = r & 255;
    const float* sp = seg == 0 ? lWh0 : seg == 1 ? lWi1 : seg == 2 ? lWh1 : seg == 3 ? lWi2 : lWh2;
    u16* dp = seg == 0 ? WThh0b : seg == 1 ? WTih1b : seg == 2 ? WThh1b : seg == 3 ? WTih2b : WThh2b;
    dp[r] = f2bf(sp[jj * 64 + k]);
  }
}

// ---------------- fully fused GGNN + Set2Set: one block = one graph ----------------
// R17 = R15 restored (best measured: 683us total / 573us k_ggnn). R16's explicit
// cross-node gather pipelining was null -> source-level latency levers exhausted.
// Structure: 1024 thr (64-VGPR hard cap, R6-R8), 1 block/CU (143.7KB LDS), 3-phase
// transform+gather with register accs (26 floats, spill-free after R12/R15),
// fp32 h in LDS, de-hoisted transform B-frags (R15).

__global__ void __launch_bounds__(NTHR) k_ggnn(
    const float* __restrict__ feats,
    const u16* __restrict__ WeTb, const float* __restrict__ b_edge,
    const u16* __restrict__ Wihb, const u16* __restrict__ Whhb,
    const float* __restrict__ gbih, const float* __restrict__ gbhh,
    const u16* __restrict__ recs, const int* __restrict__ rows,
    const u16* __restrict__ WTih0b, const u16* __restrict__ WThh0b,
    const u16* __restrict__ WTih1b, const u16* __restrict__ WThh1b,
    const u16* __restrict__ WTih2b, const u16* __restrict__ WThh2b,
    const float* __restrict__ b_ih0, const float* __restrict__ b_hh0,
    const float* __restrict__ b_ih1, const float* __restrict__ b_hh1,
    const float* __restrict__ b_ih2, const float* __restrict__ b_hh2,
    const float* __restrict__ Wp, const float* __restrict__ bp,
    float* __restrict__ out) {
  __shared__ __align__(16) u16 hb_s[NPAD * 64];      // bf16 h (swizzled)   26624B
  __shared__ __align__(16) u16 wh_s[2 * NPAD * 64];  // 2-etype Wh / ab     53248B
  __shared__ __align__(16) float h32_s[NPG * 64];    // fp32 h / feat_s     51200B
  __shared__ __align__(16) char u_s[12656];          // rec+rows | s2s      12656B
  // total ~143.7KB -> 1 block/CU

  u16* rec_s = (u16*)u_s;               // 10240B (steps)
  int* rows_s = (int*)(u_s + 10240);    //  2412B (steps)
  float* qstar = (float*)u_s;           // s2s overlay:
  float* xbuf = (float*)(u_s + 512);    //
  float* hs_f = (float*)(u_s + 768);    // [3][64]
  float* cs_f = (float*)(u_s + 1536);   // [3][64]
  float* gates = (float*)(u_s + 2304);  // [256]
  float* gpart = (float*)(u_s + 3328);  // [4][256]
  float* e_s = (float*)(u_s + 7424);    // [200]
  float* red_f = (float*)(u_s + 8224);  // [16][64]
  float* scal = (float*)(u_s + 12320);  // [2]

  int g = blockIdx.x, tid = threadIdx.x;
  int lane = tid & 63, wid = tid >> 6;  // 16 waves
  int m = lane & 15, quad = lane >> 4;
  int half = lane >> 5, l32 = lane & 31;

  // ---- stage graph-local state ----
  const float* fg = feats + (size_t)g * (NPG * 64);
  for (int i = tid; i < NPG * 64; i += NTHR) {
    float v = fg[i];
    h32_s[i] = v;
    hb_s[swz(i >> 6, i & 63)] = f2bf(v);
  }
  for (int i = tid; i < (NPAD - NPG) * 64; i += NTHR) hb_s[NPG * 64 + i] = 0;  // pad rows
  // zero wh pad rows 200..207 of BOTH halves (preserved: nothing else writes them)
  for (int i = tid; i < 2 * 8 * 64; i += NTHR) {
    int tl = i >> 9, rem = i & 511;
    wh_s[(tl * NPAD + NPG + (rem >> 6)) * 64 + (rem & 63)] = 0;
  }
  {
    const u32* r32 = (const u32*)(recs + (size_t)g * EPG_P);
    u32* rl = (u32*)rec_s;
    for (int i = tid; i < EPG_P / 2; i += NTHR) rl[i] = r32[i];
  }
  for (int i = tid; i < 3 * (NPG + 1); i += NTHR) rows_s[i] = rows[g * 3 * (NPG + 1) + i];

  u16* ab_s = wh_s;  // alias: wh dead once gathers finish; flush writes rows<200 only
  int ot = wid & 3, hh = wid >> 2;  // hh in 0..3

// 13 named gather accumulator pairs: node n = q*16+wid, 2 cols per lane,
// accumulated across ALL 3 phases, halves combined at flush.
#define ACC_DECL(q) float a0_##q, a1_##q;
  REP13(ACC_DECL)
#define ACC_ZERO(q) a0_##q = 0.f; a1_##q = 0.f;
#define GATHER(q)                                              \
  {                                                            \
    int n = (q)*16 + wid;                                      \
    if (n < NPG) {                                             \
      int rs = rowp[n], re = rowp[n + 1];                      \
      for (int e = rs; e < re; e += 4) {                       \
        int pA = rec_s[e + half];                              \
        int pB = rec_s[e + 2 + half];                          \
        u32 wA = *(const u32*)(wh_s + pA * 64 + 2 * l32);      \
        u32 wB = *(const u32*)(wh_s + pB * 64 + 2 * l32);      \
        a0_##q += bflo(wA) + bflo(wB);                         \
        a1_##q += bfhi(wA) + bfhi(wB);                         \
      }                                                        \
    }                                                          \
  }
#define FLUSH(q)                                                   \
  {                                                                \
    int n = (q)*16 + wid;                                          \
    float s0 = a0_##q + __shfl_xor(a0_##q, 32);                    \
    float s1 = a1_##q + __shfl_xor(a1_##q, 32);                    \
    if (n < NPG && lane < 32) {                                    \
      u32 pk = (u32)f2bf(s0) | ((u32)f2bf(s1) << 16);              \
      *(u32*)(ab_s + n * 64 + ((2 * l32) ^ ((n & 7) << 3))) = pk;  \
    }                                                              \
  }

#pragma unroll 1
  for (int step = 0; step < NSTEPS; step++) {
    REP13(ACC_ZERO)
#pragma unroll 1
    for (int ph = 0; ph < 3; ph++) {
      __syncthreads();  // wh_s/ab_s free (prev gather read / prev GRU read / staging)
      // ---- transform etypes {2ph, 2ph+1} -> wh_s halves ----
      // B-fragments reloaded from L2 per iteration (NOT hoisted): keeps the 26
      // gather accs register-resident across the transform (R12 spilled them).
      for (int nt = hh; nt < NTILES; nt += 4) {  // tl = 0
        const u16* bp0 = WeTb + (((2 * ph) * 64 + ot * 16 + m) * 64) + quad * 8;
        bf16x8 B00 = *(const bf16x8*)bp0;
        bf16x8 B01 = *(const bf16x8*)(bp0 + 32);
        int arow = nt * 16 + m;
        bf16x8 a0 = *(const bf16x8*)(hb_s + swz(arow, quad * 8));
        bf16x8 a1 = *(const bf16x8*)(hb_s + swz(arow, quad * 8 + 32));
        f32x4 c = {0.f, 0.f, 0.f, 0.f};
        c = __builtin_amdgcn_mfma_f32_16x16x32_bf16(a0, B00, c, 0, 0, 0);
        c = __builtin_amdgcn_mfma_f32_16x16x32_bf16(a1, B01, c, 0, 0, 0);
        float bias0 = b_edge[(2 * ph) * 64 + ot * 16 + m];
#pragma unroll
        for (int r = 0; r < 4; r++) {
          int node = nt * 16 + quad * 4 + r;
          if (node < NPG) wh_s[node * 64 + ot * 16 + m] = f2bf(c[r] + bias0);
        }
      }
      for (int nt = 3 - hh; nt < NTILES; nt += 4) {  // tl = 1 (reversed for balance)
        const u16* bp1 = WeTb + (((2 * ph + 1) * 64 + ot * 16 + m) * 64) + quad * 8;
        bf16x8 B10 = *(const bf16x8*)bp1;
        bf16x8 B11 = *(const bf16x8*)(bp1 + 32);
        int arow = nt * 16 + m;
        bf16x8 a0 = *(const bf16x8*)(hb_s + swz(arow, quad * 8));
        bf16x8 a1 = *(const bf16x8*)(hb_s + swz(arow, quad * 8 + 32));
        f32x4 c = {0.f, 0.f, 0.f, 0.f};
        c = __builtin_amdgcn_mfma_f32_16x16x32_bf16(a0, B10, c, 0, 0, 0);
        c = __builtin_amdgcn_mfma_f32_16x16x32_bf16(a1, B11, c, 0, 0, 0);
        float bias1 = b_edge[(2 * ph + 1) * 64 + ot * 16 + m];
#pragma unroll
        for (int r = 0; r < 4; r++) {
          int node = nt * 16 + quad * 4 + r;
          if (node < NPG) wh_s[(NPAD + node) * 64 + ot * 16 + m] = f2bf(c[r] + bias1);
        }
      }
      __syncthreads();  // wh ready
      // ---- gather: padded x4 lists, half-wave per edge, accumulate in regs ----
      const int* rowp = rows_s + ph * (NPG + 1);
      REP13(GATHER)
    }
    __syncthreads();  // all gathers done reading wh_s -> reuse as ab_s
    REP13(FLUSH)
    __syncthreads();  // ab ready
    // ---- GRU: wave wid owns tile nt=wid; per-dq fragments (16 acc regs) ----
    if (wid < NTILES) {
      int nt = wid;
      int arow = nt * 16 + m;
      bf16x8 aa0 = *(const bf16x8*)(ab_s + swz(arow, quad * 8));
      bf16x8 aa1 = *(const bf16x8*)(ab_s + swz(arow, quad * 8 + 32));
      bf16x8 ah0 = *(const bf16x8*)(hb_s + swz(arow, quad * 8));
      bf16x8 ah1 = *(const bf16x8*)(hb_s + swz(arow, quad * 8 + 32));
#pragma unroll
      for (int dq = 0; dq < 4; dq++) {
        int d = dq * 16 + m;
        f32x4 z4 = {0.f, 0.f, 0.f, 0.f};
        const u16* bi = Wihb + (dq * 16 + m) * 64 + quad * 8;
        const u16* bh = Whhb + (dq * 16 + m) * 64 + quad * 8;
        f32x4 cr = z4;
        {
          bf16x8 b0 = *(const bf16x8*)bi, b1 = *(const bf16x8*)(bi + 32);
          bf16x8 c0 = *(const bf16x8*)bh, c1 = *(const bf16x8*)(bh + 32);
          cr = __builtin_amdgcn_mfma_f32_16x16x32_bf16(ah0, c0, cr, 0, 0, 0);
          cr = __builtin_amdgcn_mfma_f32_16x16x32_bf16(ah1, c1, cr, 0, 0, 0);
          cr = __builtin_amdgcn_mfma_f32_16x16x32_bf16(aa0, b0, cr, 0, 0, 0);
          cr = __builtin_amdgcn_mfma_f32_16x16x32_bf16(aa1, b1, cr, 0, 0, 0);
        }
        const u16* bi2 = Wihb + ((4 + dq) * 16 + m) * 64 + quad * 8;
        const u16* bh2 = Whhb + ((4 + dq) * 16 + m) * 64 + quad * 8;
        f32x4 cz = z4;
        {
          bf16x8 b0 = *(const bf16x8*)bi2, b1 = *(const bf16x8*)(bi2 + 32);
          bf16x8 c0 = *(const bf16x8*)bh2, c1 = *(const bf16x8*)(bh2 + 32);
          cz = __builtin_amdgcn_mfma_f32_16x16x32_bf16(ah0, c0, cz, 0, 0, 0);
          cz = __builtin_amdgcn_mfma_f32_16x16x32_bf16(ah1, c1, cz, 0, 0, 0);
          cz = __builtin_amdgcn_mfma_f32_16x16x32_bf16(aa0, b0, cz, 0, 0, 0);
          cz = __builtin_amdgcn_mfma_f32_16x16x32_bf16(aa1, b1, cz, 0, 0, 0);
        }
        const u16* bi3 = Wihb + ((8 + dq) * 16 + m) * 64 + quad * 8;
        const u16* bh3 = Whhb + ((8 + dq) * 16 + m) * 64 + quad * 8;
        f32x4 ci = z4, ch = z4;
        {
          bf16x8 b0 = *(const bf16x8*)bi3, b1 = *(const bf16x8*)(bi3 + 32);
          bf16x8 c0 = *(const bf16x8*)bh3, c1 = *(const bf16x8*)(bh3 + 32);
          ci = __builtin_amdgcn_mfma_f32_16x16x32_bf16(aa0, b0, ci, 0, 0, 0);
          ci = __builtin_amdgcn_mfma_f32_16x16x32_bf16(aa1, b1, ci, 0, 0, 0);
          ch = __builtin_amdgcn_mfma_f32_16x16x32_bf16(ah0, c0, ch, 0, 0, 0);
          ch = __builtin_amdgcn_mfma_f32_16x16x32_bf16(ah1, c1, ch, 0, 0, 0);
        }
        float bi_r = gbih[d], bh_r = gbhh[d];
        float bi_z = gbih[64 + d], bh_z = gbhh[64 + d];
        float bi_n = gbih[128 + d], bh_n = gbhh[128 + d];
#pragma unroll
        for (int r = 0; r < 4; r++) {
          int node = nt * 16 + quad * 4 + r;
          if (node < NPG) {
            float rr = sigmf(cr[r] + bi_r + bh_r);
            float zz = sigmf(cz[r] + bi_z + bh_z);
            float nn = tanhf(ci[r] + bi_n + rr * (ch[r] + bh_n));
            float hv = h32_s[node * 64 + d];
            float hnew = (1.0f - zz) * nn + zz * hv;
            h32_s[node * 64 + d] = hnew;
            hb_s[swz(node, d)] = f2bf(hnew);
          }
        }
      }
    }
  }
  __syncthreads();  // final h (feat_s = h32_s) ready; u_s becomes s2s scratch
  const float* feat_s = h32_s;

  // ================= Set2Set: 4-part matvec, weights streamed from L2 =================
  int j = tid & 255, part = tid >> 8;  // wave-uniform part in 0..3
  float bs0 = 0.f, bs1 = 0.f, bs2 = 0.f;
  if (tid < 256) {
    bs0 = b_ih0[tid] + b_hh0[tid];
    bs1 = b_ih1[tid] + b_hh1[tid];
    bs2 = b_ih2[tid] + b_hh2[tid];
  }
  __syncthreads();  // rec_s/rows_s dead before overlay writes
  if (tid < 128) qstar[tid] = 0.f;
  if (tid < 64) {
    xbuf[tid] = 0.f;
    for (int l = 0; l < 3; l++) {
      hs_f[l * 64 + tid] = 0.f;
      cs_f[l * 64 + tid] = 0.f;
    }
  }
  __syncthreads();
#pragma unroll 1
  for (int it = 0; it < NITERS; it++) {
    // ---- layer 0 ----
    {
      float a0 = 0.f;
      if (part == 0) {
#pragma unroll 8
        for (int k = 0; k < 48; k++) a0 += qstar[k] * bf2f(WTih0b[k * 256 + j]);
      } else if (part == 1) {
#pragma unroll 8
        for (int k = 48; k < 96; k++) a0 += qstar[k] * bf2f(WTih0b[k * 256 + j]);
      } else if (part == 2) {
#pragma unroll 8
        for (int k = 96; k < 128; k++) a0 += qstar[k] * bf2f(WTih0b[k * 256 + j]);
#pragma unroll 8
        for (int k = 0; k < 16; k++) a0 += hs_f[k] * bf2f(WThh0b[k * 256 + j]);
      } else {
#pragma unroll 8
        for (int k = 16; k < 64; k++) a0 += hs_f[k] * bf2f(WThh0b[k * 256 + j]);
      }
      gpart[part * 256 + j] = a0;
    }
    __syncthreads();
    if (tid < 256)
      gates[tid] = gpart[tid] + gpart[256 + tid] + gpart[512 + tid] + gpart[768 + tid] + bs0;
    __syncthreads();
    if (tid < 64) {
      float cc = sigmf(gates[64 + tid]) * cs_f[tid] + sigmf(gates[tid]) * tanhf(gates[128 + tid]);
      float x = sigmf(gates[192 + tid]) * tanhf(cc);
      cs_f[tid] = cc;
      hs_f[tid] = x;
      xbuf[tid] = x;
    }
    __syncthreads();
    // ---- layers 1,2 ----
#pragma unroll 1
    for (int l = 1; l < 3; l++) {
      const u16* W = (l == 1) ? ((part < 2) ? WTih1b : WThh1b)
                              : ((part < 2) ? WTih2b : WThh2b);
      const float* xv = (part < 2) ? xbuf : (hs_f + l * 64);
      int k0 = (part & 1) * 32;
      float a0 = 0.f;
#pragma unroll 8
      for (int k = k0; k < k0 + 32; k++) a0 += xv[k] * bf2f(W[k * 256 + j]);
      gpart[part * 256 + j] = a0;
      __syncthreads();
      float bsl = (l == 1) ? bs1 : bs2;
      if (tid < 256)
        gates[tid] = gpart[tid] + gpart[256 + tid] + gpart[512 + tid] + gpart[768 + tid] + bsl;
      __syncthreads();
      if (tid < 64) {
        float cc = sigmf(gates[64 + tid]) * cs_f[l * 64 + tid] +
                   sigmf(gates[tid]) * tanhf(gates[128 + tid]);
        float x = sigmf(gates[192 + tid]) * tanhf(cc);
        cs_f[l * 64 + tid] = cc;
        hs_f[l * 64 + tid] = x;
        xbuf[tid] = x;
      }
      __syncthreads();
    }
    // ---- attention over this graph's nodes ----
    for (int n = wid; n < NPG; n += 16) {
      float v = feat_s[n * 64 + lane] * xbuf[lane];
      for (int off = 32; off > 0; off >>= 1) v += __shfl_down(v, off);
      if (lane == 0) e_s[n] = v;
    }
    __syncthreads();
    if (tid < 64) {
      float mx = -1e30f;
      for (int n = lane; n < NPG; n += 64) mx = fmaxf(mx, e_s[n]);
      for (int off = 32; off > 0; off >>= 1) mx = fmaxf(mx, __shfl_down(mx, off));
      mx = __shfl(mx, 0);
      float ssum = 0.f;
      for (int n = lane; n < NPG; n += 64) {
        float ex = __expf(e_s[n] - mx);
        e_s[n] = ex;
        ssum += ex;
      }
      for (int off = 32; off > 0; off >>= 1) ssum += __shfl_down(ssum, off);
      if (lane == 0) scal[0] = ssum;
    }
    __syncthreads();
    float denom = scal[0];
    {
      float r = 0.f;
      for (int n = wid; n < NPG; n += 16) r += feat_s[n * 64 + lane] * e_s[n];
      red_f[wid * 64 + lane] = r;
    }
    __syncthreads();
    if (tid < 64) {
      float ro = 0.f;
#pragma unroll
      for (int ww = 0; ww < 16; ww++) ro += red_f[ww * 64 + lane];
      qstar[lane] = xbuf[lane];
      qstar[64 + lane] = ro / denom;
    }
    __syncthreads();
  }
  if (tid < 3) {
    float s = bp[tid];
    for (int k = 0; k < 128; k++) s += qstar[k] * Wp[tid * 128 + k];
    out[g * 3 + tid] = s;
  }
}

// ---------------- host ----------------

extern "C" void kernel_launch(void* const* d_in, const int* in_sizes, int n_in,
                              void* d_out, int out_size, void* d_ws, size_t ws_size,
                              hipStream_t stream) {
  const float* feats  = (const float*)d_in[0];
  const float* W_edge = (const float*)d_in[1];
  const float* b_edge = (const float*)d_in[2];
  const float* gWih   = (const float*)d_in[3];
  const float* gWhh   = (const float*)d_in[4];
  const float* gbih   = (const float*)d_in[5];
  const float* gbhh   = (const float*)d_in[6];
  const float* lWi0   = (const float*)d_in[7];
  const float* lWh0   = (const float*)d_in[8];
  const float* lbi0   = (const float*)d_in[9];
  const float* lbh0   = (const float*)d_in[10];
  const float* lWi1   = (const float*)d_in[11];
  const float* lWh1   = (const float*)d_in[12];
  const float* lbi1   = (const float*)d_in[13];
  const float* lbh1   = (const float*)d_in[14];
  const float* lWi2   = (const float*)d_in[15];
  const float* lWh2   = (const float*)d_in[16];
  const float* lbi2   = (const float*)d_in[17];
  const float* lbh2   = (const float*)d_in[18];
  const float* Wp     = (const float*)d_in[19];
  const float* bp     = (const float*)d_in[20];
  const int* src      = (const int*)d_in[21];
  const int* dst      = (const int*)d_in[22];
  const int* ety      = (const int*)d_in[23];
  float* out = (float*)d_out;

  char* ws = (char*)d_ws;
  u16* recs    = (u16*)ws;              // 3,276,800 B (320 x 5120 x 2)
  int* rows    = (int*)(ws + 3276800);  //   771,840 B (320 x 3 x 201)
  u16* WeTb    = (u16*)(ws + 4048640);  //    49,152 B
  u16* Wihb    = (u16*)(ws + 4097792);  //    24,576 B
  u16* Whhb    = (u16*)(ws + 4122368);  //    24,576 B
  u16* WTih0b  = (u16*)(ws + 4146944);  //    65,536 B
  u16* WThh0b  = (u16*)(ws + 4212480);  //    32,768 B
  u16* WTih1b  = (u16*)(ws + 4245248);  //    32,768 B
  u16* WThh1b  = (u16*)(ws + 4278016);  //    32,768 B
  u16* WTih2b  = (u16*)(ws + 4310784);  //    32,768 B
  u16* WThh2b  = (u16*)(ws + 4343552);  //    32,768 B

  k_csr<<<NGRAPH, 256, 0, stream>>>(src, dst, ety, recs, rows);
  k_prep<<<640, 256, 0, stream>>>(W_edge, gWih, gWhh, lWi0, lWh0, lWi1, lWh1, lWi2, lWh2,
                                  WeTb, Wihb, Whhb, WTih0b, WThh0b, WTih1b, WThh1b, WTih2b, WThh2b);
  k_ggnn<<<NGRAPH, NTHR, 0, stream>>>(feats, WeTb, b_edge, Wihb, Whhb, gbih, gbhh, recs, rows,
                                      WTih0b, WThh0b, WTih1b, WThh1b, WTih2b, WThh2b,
                                      lbi0, lbh0, lbi1, lbh1, lbi2, lbh2, Wp, bp, out);
}